// Round 5
// baseline (2339.790 us; speedup 1.0000x reference)
//
#include <hip/hip_runtime.h>

typedef __attribute__((ext_vector_type(8))) short short8;
typedef __attribute__((ext_vector_type(4))) float f32x4;

#define DD 128
#define HH 256

__device__ __forceinline__ unsigned short f2bf(float f) {
  unsigned int u = __float_as_uint(f);
  u += 0x7fffu + ((u >> 16) & 1u);
  return (unsigned short)(u >> 16);
}
__device__ __forceinline__ float bf2f(unsigned short s) {
  return __uint_as_float(((unsigned int)s) << 16);
}
__device__ __forceinline__ f32x4 mfma16(short8 a, short8 b, f32x4 c) {
  return __builtin_amdgcn_mfma_f32_16x16x32_bf16(a, b, c, 0, 0, 0);
}
__device__ __forceinline__ short8 cvt8(float4 a, float4 b) {
  union { ushort4 u[2]; short8 s; } x;
  x.u[0] = make_ushort4(f2bf(a.x), f2bf(a.y), f2bf(a.z), f2bf(a.w));
  x.u[1] = make_ushort4(f2bf(b.x), f2bf(b.y), f2bf(b.z), f2bf(b.w));
  return x.s;
}

// gather one 256B h-row chunk (32 cols) into 4 short8 regs
__device__ __forceinline__ void gather_row(
    const unsigned short* hbf, const float* hidden, int si, int pi, int part,
    short8& g0, short8& g1, short8& g2, short8& g3) {
  if (hbf) {
    const unsigned short* s = (part < 4) ? hbf + (size_t)si * DD + part * 32
                                         : hbf + (size_t)pi * DD + (part - 4) * 32;
    g0 = *(const short8*)(s);
    g1 = *(const short8*)(s + 8);
    g2 = *(const short8*)(s + 16);
    g3 = *(const short8*)(s + 24);
  } else {
    const float* s = (part < 4) ? hidden + (size_t)si * DD + part * 32
                                : hidden + (size_t)pi * DD + (part - 4) * 32;
    float4 a, b;
    a = *(const float4*)(s);      b = *(const float4*)(s + 4);  g0 = cvt8(a, b);
    a = *(const float4*)(s + 8);  b = *(const float4*)(s + 12); g1 = cvt8(a, b);
    a = *(const float4*)(s + 16); b = *(const float4*)(s + 20); g2 = cvt8(a, b);
    a = *(const float4*)(s + 24); b = *(const float4*)(s + 28); g3 = cvt8(a, b);
  }
}

// ---- fused weight convert for all 8 matrices: dst[n][k] = bf16(src[(k+kswap)%K][n])
__global__ void wconv_all(const float* __restrict__ s0, const float* __restrict__ s1,
                          const float* __restrict__ s2, const float* __restrict__ s3,
                          const float* __restrict__ s4, const float* __restrict__ s5,
                          const float* __restrict__ s6, const float* __restrict__ s7,
                          unsigned short* __restrict__ d0, unsigned short* __restrict__ d1,
                          unsigned short* __restrict__ d2, unsigned short* __restrict__ d3,
                          unsigned short* __restrict__ d4, unsigned short* __restrict__ d5,
                          unsigned short* __restrict__ d6, unsigned short* __restrict__ d7) {
  int id = blockIdx.x * 256 + threadIdx.x;
  const float* src; unsigned short* dst; int K, Nout, kswap = 0, base;
  if (id < 32768)       { src = s0; dst = d0; K = 128; Nout = 256; base = 0; }
  else if (id < 65536)  { src = s1; dst = d1; K = 256; Nout = 128; base = 32768; }
  else if (id < 131072) { src = s2; dst = d2; K = 256; Nout = 256; base = 65536; kswap = 128; }
  else if (id < 163840) { src = s3; dst = d3; K = 256; Nout = 128; base = 131072; }
  else if (id < 229376) { src = s4; dst = d4; K = 256; Nout = 256; base = 163840; }
  else if (id < 262144) { src = s5; dst = d5; K = 256; Nout = 128; base = 229376; }
  else if (id < 360448) { src = s6; dst = d6; K = 384; Nout = 256; base = 262144; }
  else if (id < 393216) { src = s7; dst = d7; K = 256; Nout = 128; base = 360448; }
  else return;
  int lid = id - base;
  int n = lid / K, k = lid - n * K;
  int ks = k + kswap; if (ks >= K) ks -= K;
  dst[n * K + k] = f2bf(src[(size_t)ks * Nout + n]);
}

// ---- edge vectors + fold edge constants into layer-1 biases (1 block, 256 thr)
__global__ void prep_bias(const float* __restrict__ Ew1, const float* __restrict__ Eb1,
                          const float* __restrict__ Ew2, const float* __restrict__ Eb2,
                          const float* __restrict__ Pw1, const float* __restrict__ Pb1,
                          const float* __restrict__ Cw1, const float* __restrict__ Cb1,
                          float* __restrict__ b1P, float* __restrict__ b1C) {
  __shared__ float h1[HH], h0[HH], ein[DD], eout[DD];
  int t = threadIdx.x;
  h1[t] = fmaxf(Ew1[t] + Eb1[t], 0.f);
  h0[t] = fmaxf(Eb1[t], 0.f);
  __syncthreads();
  if (t < DD) {
    float s1 = Eb2[t], s0 = Eb2[t];
    for (int j = 0; j < HH; ++j) { s1 += h1[j] * Ew2[j * DD + t]; s0 += h0[j] * Ew2[j * DD + t]; }
    ein[t]  = fmaxf(s1, 0.f);
    eout[t] = fmaxf(s0, 0.f);
  }
  __syncthreads();
  float bp = Pb1[t], bc = Cb1[t];
  for (int d = 0; d < DD; ++d) {
    bp += eout[d] * Pw1[(size_t)(256 + d) * HH + t];
    bc += ein[d]  * Cw1[(size_t)(256 + d) * HH + t];
  }
  b1P[t] = bp; b1C[t] = bc;
}

// ---- CSR build
__global__ void count_k(const int* __restrict__ selfI, const int* __restrict__ parI,
                        int* degP, int* degC, int E) {
  int id = blockIdx.x * 256 + threadIdx.x;
  if (id < E) { atomicAdd(&degP[selfI[id]], 1); atomicAdd(&degC[parI[id]], 1); }
}

__global__ void scan1_2(const int* __restrict__ srcA, int* __restrict__ dstA, int* __restrict__ partA,
                        const int* __restrict__ srcB, int* __restrict__ dstB, int* __restrict__ partB,
                        int n) {
  const int* src = blockIdx.y ? srcB : srcA;
  int* dst = blockIdx.y ? dstB : dstA;
  int* part = blockIdx.y ? partB : partA;
  __shared__ int sh[256];
  int t = threadIdx.x;
  int base = blockIdx.x * 1024 + t * 4;
  int v0 = base + 0 < n ? src[base + 0] : 0;
  int v1 = base + 1 < n ? src[base + 1] : 0;
  int v2 = base + 2 < n ? src[base + 2] : 0;
  int v3 = base + 3 < n ? src[base + 3] : 0;
  int tsum = v0 + v1 + v2 + v3;
  sh[t] = tsum;
  __syncthreads();
  for (int off = 1; off < 256; off <<= 1) {
    int y = (t >= off) ? sh[t - off] : 0;
    __syncthreads();
    if (t >= off) sh[t] += y;
    __syncthreads();
  }
  int ex = sh[t] - tsum;
  if (base + 0 < n) dst[base + 0] = ex;
  if (base + 1 < n) dst[base + 1] = ex + v0;
  if (base + 2 < n) dst[base + 2] = ex + v0 + v1;
  if (base + 3 < n) dst[base + 3] = ex + v0 + v1 + v2;
  if (t == 255) part[blockIdx.x] = sh[255];
}

__global__ void scan2_2(int* __restrict__ partA, int* __restrict__ partB, int m) {
  int* part = blockIdx.x ? partB : partA;
  __shared__ int sh[256];
  int t = threadIdx.x;
  int carry = 0;
  for (int base = 0; base < m; base += 256) {
    int v = (base + t < m) ? part[base + t] : 0;
    sh[t] = v;
    __syncthreads();
    for (int off = 1; off < 256; off <<= 1) {
      int y = (t >= off) ? sh[t - off] : 0;
      __syncthreads();
      if (t >= off) sh[t] += y;
      __syncthreads();
    }
    if (base + t < m) part[base + t] = carry + sh[t] - v;
    int tot = sh[255];
    __syncthreads();
    carry += tot;
  }
}

__global__ void scan3copy(int* __restrict__ offP, const int* __restrict__ partA, int* __restrict__ curP,
                          int* __restrict__ offC, const int* __restrict__ partB, int* __restrict__ curC,
                          int n) {
  int i = blockIdx.x * 256 + threadIdx.x;
  if (i < n) {
    int a = offP[i] + partA[i >> 10];
    int b = offC[i] + partB[i >> 10];
    offP[i] = a; curP[i] = a;
    offC[i] = b; curC[i] = b;
  }
}

__global__ void pos_k(const int* __restrict__ selfI, const int* __restrict__ parI,
                      int* curP, int* curC, int* posP, int* posC, int E) {
  int e = blockIdx.x * 256 + threadIdx.x;
  if (e < E) {
    posP[e] = atomicAdd(&curP[selfI[e]], 1);
    posC[e] = atomicAdd(&curC[parI[e]], 1);
  }
}

// ---- CSR-P reorder (slot = posP[e], bijective)
__global__ void reorder_k(const int* __restrict__ selfI, const int* __restrict__ parI,
                          const int* __restrict__ posP, const int* __restrict__ posC,
                          int* __restrict__ selfS, int* __restrict__ parS,
                          int* __restrict__ posCS, int E) {
  int e = blockIdx.x * 256 + threadIdx.x;
  if (e < E) {
    int slot = posP[e];
    selfS[slot] = selfI[e];
    parS[slot] = parI[e];
    posCS[slot] = posC[e];
  }
}

// ---- cooperative MLP_V: 512 thr / 8 waves. K=128 -> 256 -> 128.
__global__ __launch_bounds__(512, 4) void v_kernel(
    const float* __restrict__ x, const unsigned short* __restrict__ W1t,
    const unsigned short* __restrict__ W2t, const float* __restrict__ b1,
    const float* __restrict__ b2, float* __restrict__ hidden,
    unsigned short* __restrict__ hbf, int n) {
  __shared__ __align__(16) unsigned short A[64 * 136];
  __shared__ __align__(16) unsigned short O1[64 * 264];
  int t = threadIdx.x;
  int w = t >> 6, lane = t & 63, ln = lane & 15, quad = lane >> 4, qo = quad * 8;
  long tile0 = (long)blockIdx.x * 64;
  int rl = t >> 3, part = t & 7;
  int c0 = part * 16;
  long gr = tile0 + rl;
  const float* src = x + (size_t)(gr < n ? gr : 0) * DD + c0;
  unsigned short* arow = A + rl * 136 + c0;
#pragma unroll
  for (int i = 0; i < 4; ++i) {
    float4 v = *(const float4*)(src + i * 4);
    *(ushort4*)(arow + i * 4) = make_ushort4(f2bf(v.x), f2bf(v.y), f2bf(v.z), f2bf(v.w));
  }
  __syncthreads();
  f32x4 acc[4][2];
#pragma unroll
  for (int m = 0; m < 4; ++m) {
    acc[m][0] = {0.f, 0.f, 0.f, 0.f}; acc[m][1] = {0.f, 0.f, 0.f, 0.f};
  }
#pragma unroll
  for (int kt = 0; kt < 4; ++kt) {
    short8 a[4];
#pragma unroll
    for (int m = 0; m < 4; ++m)
      a[m] = *(const short8*)(A + (m * 16 + ln) * 136 + kt * 32 + qo);
#pragma unroll
    for (int nn = 0; nn < 2; ++nn) {
      short8 b = *(const short8*)(W1t + (size_t)(w * 32 + nn * 16 + ln) * 128 + kt * 32 + qo);
#pragma unroll
      for (int m = 0; m < 4; ++m) acc[m][nn] = mfma16(a[m], b, acc[m][nn]);
    }
  }
#pragma unroll
  for (int nn = 0; nn < 2; ++nn) {
    int col = w * 32 + nn * 16 + ln;
    float bb = b1[col];
#pragma unroll
    for (int m = 0; m < 4; ++m)
#pragma unroll
      for (int r = 0; r < 4; ++r)
        O1[(m * 16 + quad * 4 + r) * 264 + col] = f2bf(fmaxf(acc[m][nn][r] + bb, 0.f));
  }
  __syncthreads();
  f32x4 acc2[4];
#pragma unroll
  for (int m = 0; m < 4; ++m) acc2[m] = {0.f, 0.f, 0.f, 0.f};
#pragma unroll
  for (int kt = 0; kt < 8; ++kt) {
    short8 b = *(const short8*)(W2t + (size_t)(w * 16 + ln) * 256 + kt * 32 + qo);
#pragma unroll
    for (int m = 0; m < 4; ++m) {
      short8 a = *(const short8*)(O1 + (m * 16 + ln) * 264 + kt * 32 + qo);
      acc2[m] = mfma16(a, b, acc2[m]);
    }
  }
  {
    int col = w * 16 + ln;
    float bb = b2[col];
#pragma unroll
    for (int m = 0; m < 4; ++m)
#pragma unroll
      for (int r = 0; r < 4; ++r) {
        long gr2 = tile0 + m * 16 + quad * 4 + r;
        if (gr2 < n) {
          float v = fmaxf(acc2[m][r] + bb, 0.f);
          hidden[gr2 * DD + col] = v;
          if (hbf) hbf[gr2 * DD + col] = f2bf(v);
        }
      }
  }
}

// ---- PERSISTENT pipelined edge kernel: 512 blocks grid-stride over tiles.
// Next tile's index loads issue after B1 (hide under L1); next gather issues
// after B2 (hides under P-layer2). Bias values hoisted out of the loop.
__global__ __launch_bounds__(512, 4) void edge_kernel(
    const float* __restrict__ hidden, const unsigned short* __restrict__ hbf,
    const int* __restrict__ selfS, const int* __restrict__ parS,
    const int* __restrict__ posCS,
    const unsigned short* __restrict__ Pw1t, const unsigned short* __restrict__ Pw2t,
    const unsigned short* __restrict__ Cw1t, const unsigned short* __restrict__ Cw2t,
    const float* __restrict__ b1P, const float* __restrict__ b1C,
    const float* __restrict__ b2P, const float* __restrict__ b2C,
    unsigned short* __restrict__ SpE, unsigned short* __restrict__ ScE,
    int E, int ntiles) {
  __shared__ __align__(16) unsigned short A[64 * 264];
  __shared__ __align__(16) unsigned short O1[64 * 264];
  int t = threadIdx.x;
  int w = t >> 6, lane = t & 63, ln = lane & 15, quad = lane >> 4, qo = quad * 8;
  int rl = t >> 3, part = t & 7;
  unsigned short* dstA = A + rl * 264 + part * 32;

  // hoisted per-thread bias constants
  float bbP0 = b1P[w * 32 + ln], bbP1 = b1P[w * 32 + 16 + ln];
  float bbC0 = b1C[w * 32 + ln], bbC1 = b1C[w * 32 + 16 + ln];
  float b2Pr = b2P[w * 16 + ln], b2Cr = b2C[w * 16 + ln];

  int tile = blockIdx.x;
  long ge = (long)tile * 64 + rl;
  bool vrow = (tile < ntiles) && (ge < E);
  int si = vrow ? selfS[ge] : 0;
  int pi = vrow ? parS[ge] : 0;
  int dpc = vrow ? posCS[ge] : 0;
  short8 g0, g1, g2, g3;
  gather_row(hbf, hidden, si, pi, part, g0, g1, g2, g3);

  while (tile < ntiles) {
    *(short8*)(dstA) = g0;
    *(short8*)(dstA + 8) = g1;
    *(short8*)(dstA + 16) = g2;
    *(short8*)(dstA + 24) = g3;
    __syncthreads();  // B1: A ready (also orders prev C-scatter O1 reads)

    // next-tile indices: independent loads, resolve under L1
    int ntile = tile + (int)gridDim.x;
    long ge2 = (long)ntile * 64 + rl;
    bool vrow2 = (ntile < ntiles) && (ge2 < E);
    int si2 = vrow2 ? selfS[ge2] : 0;
    int pi2 = vrow2 ? parS[ge2] : 0;
    int dpc2 = vrow2 ? posCS[ge2] : 0;

    // fused layer 1 for P and C
    f32x4 accP[4][2], accC[4][2];
#pragma unroll
    for (int m = 0; m < 4; ++m) {
      accP[m][0] = {0.f, 0.f, 0.f, 0.f}; accP[m][1] = {0.f, 0.f, 0.f, 0.f};
      accC[m][0] = {0.f, 0.f, 0.f, 0.f}; accC[m][1] = {0.f, 0.f, 0.f, 0.f};
    }
#pragma unroll
    for (int kt = 0; kt < 8; ++kt) {
      short8 a[4];
#pragma unroll
      for (int m = 0; m < 4; ++m)
        a[m] = *(const short8*)(A + (m * 16 + ln) * 264 + kt * 32 + qo);
#pragma unroll
      for (int nn = 0; nn < 2; ++nn) {
        short8 bp = *(const short8*)(Pw1t + (size_t)(w * 32 + nn * 16 + ln) * 256 + kt * 32 + qo);
        short8 bc = *(const short8*)(Cw1t + (size_t)(w * 32 + nn * 16 + ln) * 256 + kt * 32 + qo);
#pragma unroll
        for (int m = 0; m < 4; ++m) {
          accP[m][nn] = mfma16(a[m], bp, accP[m][nn]);
          accC[m][nn] = mfma16(a[m], bc, accC[m][nn]);
        }
      }
    }

    // P: O1 = relu(accP + b1P)
#pragma unroll
    for (int nn = 0; nn < 2; ++nn) {
      int col = w * 32 + nn * 16 + ln;
      float bb = nn ? bbP1 : bbP0;
#pragma unroll
      for (int m = 0; m < 4; ++m)
#pragma unroll
        for (int r = 0; r < 4; ++r)
          O1[(m * 16 + quad * 4 + r) * 264 + col] = f2bf(fmaxf(accP[m][nn][r] + bb, 0.f));
    }
    __syncthreads();  // B2: O1 ready

    // issue next-tile gather (hides under P layer 2)
    short8 n0, n1, n2, n3;
    gather_row(hbf, hidden, si2, pi2, part, n0, n1, n2, n3);

    // P layer 2
    f32x4 acc2[4];
#pragma unroll
    for (int m = 0; m < 4; ++m) acc2[m] = {0.f, 0.f, 0.f, 0.f};
#pragma unroll
    for (int kt = 0; kt < 8; ++kt) {
      short8 b = *(const short8*)(Pw2t + (size_t)(w * 16 + ln) * 256 + kt * 32 + qo);
#pragma unroll
      for (int m = 0; m < 4; ++m) {
        short8 a = *(const short8*)(O1 + (m * 16 + ln) * 264 + kt * 32 + qo);
        acc2[m] = mfma16(a, b, acc2[m]);
      }
    }
    __syncthreads();  // B3: O1 reads done
    {
      int col = w * 16 + ln;
#pragma unroll
      for (int m = 0; m < 4; ++m)
#pragma unroll
        for (int r = 0; r < 4; ++r)
          O1[(m * 16 + quad * 4 + r) * 264 + col] = f2bf(fmaxf(acc2[m][r] + b2Pr, 0.f));
    }
    __syncthreads();  // B4: repack visible
    if (vrow) {  // P store: contiguous at slot ge
      const unsigned short* srow = O1 + rl * 264 + part * 16;
      ushort4* dst = (ushort4*)(SpE + (size_t)ge * DD + part * 16);
#pragma unroll
      for (int i = 0; i < 4; ++i) dst[i] = *(const ushort4*)(srow + i * 4);
    }
    __syncthreads();  // B5: scatter LDS-reads done

    // C: O1 = relu(accC + b1C)
#pragma unroll
    for (int nn = 0; nn < 2; ++nn) {
      int col = w * 32 + nn * 16 + ln;
      float bb = nn ? bbC1 : bbC0;
#pragma unroll
      for (int m = 0; m < 4; ++m)
#pragma unroll
        for (int r = 0; r < 4; ++r)
          O1[(m * 16 + quad * 4 + r) * 264 + col] = f2bf(fmaxf(accC[m][nn][r] + bb, 0.f));
    }
    __syncthreads();  // B6
    // C layer 2
#pragma unroll
    for (int m = 0; m < 4; ++m) acc2[m] = {0.f, 0.f, 0.f, 0.f};
#pragma unroll
    for (int kt = 0; kt < 8; ++kt) {
      short8 b = *(const short8*)(Cw2t + (size_t)(w * 16 + ln) * 256 + kt * 32 + qo);
#pragma unroll
      for (int m = 0; m < 4; ++m) {
        short8 a = *(const short8*)(O1 + (m * 16 + ln) * 264 + kt * 32 + qo);
        acc2[m] = mfma16(a, b, acc2[m]);
      }
    }
    __syncthreads();  // B7
    {
      int col = w * 16 + ln;
#pragma unroll
      for (int m = 0; m < 4; ++m)
#pragma unroll
        for (int r = 0; r < 4; ++r)
          O1[(m * 16 + quad * 4 + r) * 264 + col] = f2bf(fmaxf(acc2[m][r] + b2Cr, 0.f));
    }
    __syncthreads();  // B8
    if (vrow) {  // C store: CSR-C slot
      const unsigned short* srow = O1 + rl * 264 + part * 16;
      ushort4* dst = (ushort4*)(ScE + (size_t)dpc * DD + part * 16);
#pragma unroll
      for (int i = 0; i < 4; ++i) dst[i] = *(const ushort4*)(srow + i * 4);
    }
    // rotate pipeline state (next iter's B1 orders the C-scatter O1 reads)
    tile = ntile; vrow = vrow2; ge = ge2; dpc = dpc2;
    g0 = n0; g1 = n1; g2 = n2; g3 = n3;
  }
}

// ---- node kernel: fp32 h read ONCE (A-tile + residual from regs), interleaved
// Sp/Sc mean loops (2x loads in flight), all scalars hoisted. O1 overlaid on A.
__global__ __launch_bounds__(512, 4) void node_kernel(
    float* __restrict__ hidden, unsigned short* __restrict__ hbf,
    const unsigned short* __restrict__ SpE, const unsigned short* __restrict__ ScE,
    const int* __restrict__ offP, const int* __restrict__ degP,
    const int* __restrict__ offC, const int* __restrict__ degC,
    const float* __restrict__ rootM, const float* __restrict__ leafM,
    const float* __restrict__ startT, const float* __restrict__ endT,
    const unsigned short* __restrict__ W1t, const unsigned short* __restrict__ W2t,
    const float* __restrict__ b1, const float* __restrict__ b2, int n) {
  __shared__ __align__(16) unsigned short A[64 * 392];
  int t = threadIdx.x;
  int w = t >> 6, lane = t & 63, ln = lane & 15, quad = lane >> 4, qo = quad * 8;
  long tile0 = (long)blockIdx.x * 64;
  int rl = t >> 3, part = t & 7;
  int c0 = part * 16;
  long gr = tile0 + rl;
  long g = (gr < n) ? gr : 0;
  // issue all independent loads up front: h (kept in regs for residual), CSR meta
  const float* hrow = hidden + (size_t)g * DD + c0;
  float4 h0 = *(const float4*)(hrow);
  float4 h1 = *(const float4*)(hrow + 4);
  float4 h2 = *(const float4*)(hrow + 8);
  float4 h3 = *(const float4*)(hrow + 12);
  int offp = offP[g], dgp = degP[g];
  int offc = offC[g], dgc = degC[g];
  float rm = rootM[g], lm = leafM[g];

  unsigned short* arow = A + rl * 392;
  *(ushort4*)(arow + c0)      = make_ushort4(f2bf(h0.x), f2bf(h0.y), f2bf(h0.z), f2bf(h0.w));
  *(ushort4*)(arow + c0 + 4)  = make_ushort4(f2bf(h1.x), f2bf(h1.y), f2bf(h1.z), f2bf(h1.w));
  *(ushort4*)(arow + c0 + 8)  = make_ushort4(f2bf(h2.x), f2bf(h2.y), f2bf(h2.z), f2bf(h2.w));
  *(ushort4*)(arow + c0 + 12) = make_ushort4(f2bf(h3.x), f2bf(h3.y), f2bf(h3.z), f2bf(h3.w));

  // interleaved CSR mean loops: Sp and Sc loads in flight together
  float sp[16], sc[16];
#pragma unroll
  for (int i = 0; i < 16; ++i) { sp[i] = 0.f; sc[i] = 0.f; }
  const unsigned short* rp = SpE + (size_t)offp * DD + c0;
  const unsigned short* rc = ScE + (size_t)offc * DD + c0;
  int jm = dgp > dgc ? dgp : dgc;
  for (int j = 0; j < jm; ++j) {
    if (j < dgp) {
      short8 u0 = *(const short8*)(rp);
      short8 u1 = *(const short8*)(rp + 8);
#pragma unroll
      for (int k = 0; k < 8; ++k) {
        sp[k]     += bf2f((unsigned short)u0[k]);
        sp[8 + k] += bf2f((unsigned short)u1[k]);
      }
      rp += DD;
    }
    if (j < dgc) {
      short8 u0 = *(const short8*)(rc);
      short8 u1 = *(const short8*)(rc + 8);
#pragma unroll
      for (int k = 0; k < 8; ++k) {
        sc[k]     += bf2f((unsigned short)u0[k]);
        sc[8 + k] += bf2f((unsigned short)u1[k]);
      }
      rc += DD;
    }
  }
  {
    float ip = 1.f / fmaxf((float)dgp, 1.f);
#pragma unroll
    for (int i = 0; i < 4; ++i) {
      float4 st = *(const float4*)(startT + c0 + i * 4);
      *(ushort4*)(arow + 128 + c0 + i * 4) = make_ushort4(
          f2bf(sp[i * 4 + 0] * ip + rm * st.x), f2bf(sp[i * 4 + 1] * ip + rm * st.y),
          f2bf(sp[i * 4 + 2] * ip + rm * st.z), f2bf(sp[i * 4 + 3] * ip + rm * st.w));
    }
    float ic = 1.f / fmaxf((float)dgc, 1.f);
#pragma unroll
    for (int i = 0; i < 4; ++i) {
      float4 et = *(const float4*)(endT + c0 + i * 4);
      *(ushort4*)(arow + 256 + c0 + i * 4) = make_ushort4(
          f2bf(sc[i * 4 + 0] * ic + lm * et.x), f2bf(sc[i * 4 + 1] * ic + lm * et.y),
          f2bf(sc[i * 4 + 2] * ic + lm * et.z), f2bf(sc[i * 4 + 3] * ic + lm * et.w));
    }
  }
  __syncthreads();
  // layer 1 (K=384): wave w -> cols [w*32, w*32+32)
  f32x4 acc[4][2];
#pragma unroll
  for (int m = 0; m < 4; ++m) {
    acc[m][0] = {0.f, 0.f, 0.f, 0.f}; acc[m][1] = {0.f, 0.f, 0.f, 0.f};
  }
#pragma unroll
  for (int kt = 0; kt < 12; ++kt) {
    short8 a[4];
#pragma unroll
    for (int m = 0; m < 4; ++m)
      a[m] = *(const short8*)(A + (m * 16 + ln) * 392 + kt * 32 + qo);
#pragma unroll
    for (int nn = 0; nn < 2; ++nn) {
      short8 b = *(const short8*)(W1t + (size_t)(w * 32 + nn * 16 + ln) * 384 + kt * 32 + qo);
#pragma unroll
      for (int m = 0; m < 4; ++m) acc[m][nn] = mfma16(a[m], b, acc[m][nn]);
    }
  }
  __syncthreads();  // all A reads done -> overlay O1 into A storage
#pragma unroll
  for (int nn = 0; nn < 2; ++nn) {
    int col = w * 32 + nn * 16 + ln;
    float bb = b1[col];
#pragma unroll
    for (int m = 0; m < 4; ++m)
#pragma unroll
      for (int r = 0; r < 4; ++r)
        A[(m * 16 + quad * 4 + r) * 392 + col] = f2bf(fmaxf(acc[m][nn][r] + bb, 0.f));
  }
  __syncthreads();
  // layer 2 (K=256): wave w -> cols [w*16, w*16+16)
  f32x4 acc2[4];
#pragma unroll
  for (int m = 0; m < 4; ++m) acc2[m] = {0.f, 0.f, 0.f, 0.f};
#pragma unroll
  for (int kt = 0; kt < 8; ++kt) {
    short8 b = *(const short8*)(W2t + (size_t)(w * 16 + ln) * 256 + kt * 32 + qo);
#pragma unroll
    for (int m = 0; m < 4; ++m) {
      short8 a = *(const short8*)(A + (m * 16 + ln) * 392 + kt * 32 + qo);
      acc2[m] = mfma16(a, b, acc2[m]);
    }
  }
  __syncthreads();  // O1 reads done -> overlay fp32 repack
  {
    int col = w * 16 + ln;
    float bb = b2[col];
#pragma unroll
    for (int m = 0; m < 4; ++m)
#pragma unroll
      for (int r = 0; r < 4; ++r)
        ((float*)(A + (size_t)(m * 16 + quad * 4 + r) * 392))[col] =
            fmaxf(acc2[m][r] + bb, 0.f);
  }
  __syncthreads();
  if (gr < n) {
    const float* F = (const float*)(A + (size_t)rl * 392) + c0;
    float* hout = hidden + (size_t)gr * DD + c0;
    unsigned short* brow = hbf ? hbf + (size_t)gr * DD + c0 : nullptr;
    float4 v0 = *(const float4*)(F);
    float4 v1 = *(const float4*)(F + 4);
    float4 v2 = *(const float4*)(F + 8);
    float4 v3 = *(const float4*)(F + 12);
    h0.x += v0.x; h0.y += v0.y; h0.z += v0.z; h0.w += v0.w;
    h1.x += v1.x; h1.y += v1.y; h1.z += v1.z; h1.w += v1.w;
    h2.x += v2.x; h2.y += v2.y; h2.z += v2.z; h2.w += v2.w;
    h3.x += v3.x; h3.y += v3.y; h3.z += v3.z; h3.w += v3.w;
    *(float4*)(hout) = h0;
    *(float4*)(hout + 4) = h1;
    *(float4*)(hout + 8) = h2;
    *(float4*)(hout + 12) = h3;
    if (brow) {
      *(ushort4*)(brow)     = make_ushort4(f2bf(h0.x), f2bf(h0.y), f2bf(h0.z), f2bf(h0.w));
      *(ushort4*)(brow + 4) = make_ushort4(f2bf(h1.x), f2bf(h1.y), f2bf(h1.z), f2bf(h1.w));
      *(ushort4*)(brow + 8) = make_ushort4(f2bf(h2.x), f2bf(h2.y), f2bf(h2.z), f2bf(h2.w));
      *(ushort4*)(brow + 12) = make_ushort4(f2bf(h3.x), f2bf(h3.y), f2bf(h3.z), f2bf(h3.w));
    }
  }
}

extern "C" void kernel_launch(void* const* d_in, const int* in_sizes, int n_in,
                              void* d_out, int out_size, void* d_ws, size_t ws_size,
                              hipStream_t stream) {
  const float* batch  = (const float*)d_in[0];
  const int*   selfI  = (const int*)d_in[1];
  const int*   parI   = (const int*)d_in[2];
  const float* rootM  = (const float*)d_in[3];
  const float* leafM  = (const float*)d_in[4];
  const float* startT = (const float*)d_in[5];
  const float* endT   = (const float*)d_in[6];
  const float* Vw1 = (const float*)d_in[7],  *Vb1 = (const float*)d_in[8];
  const float* Vw2 = (const float*)d_in[9],  *Vb2 = (const float*)d_in[10];
  const float* Ew1 = (const float*)d_in[11], *Eb1 = (const float*)d_in[12];
  const float* Ew2 = (const float*)d_in[13], *Eb2 = (const float*)d_in[14];
  const float* Pw1 = (const float*)d_in[15], *Pb1 = (const float*)d_in[16];
  const float* Pw2 = (const float*)d_in[17], *Pb2 = (const float*)d_in[18];
  const float* Cw1 = (const float*)d_in[19], *Cb1 = (const float*)d_in[20];
  const float* Cw2 = (const float*)d_in[21], *Cb2 = (const float*)d_in[22];
  const float* Aw1 = (const float*)d_in[23], *Ab1 = (const float*)d_in[24];
  const float* Aw2 = (const float*)d_in[25], *Ab2 = (const float*)d_in[26];

  const int N = in_sizes[3];
  const int E = in_sizes[1];
  float* out = (float*)d_out;

  char* p = (char*)d_ws;
  auto nxt = [&](size_t sz) { char* r = p; p += (sz + 255) & ~(size_t)255; return r; };
  unsigned short* SpE = (unsigned short*)nxt((size_t)E * DD * 2);
  unsigned short* ScE = (unsigned short*)nxt((size_t)E * DD * 2);
  int* degP = (int*)nxt((size_t)N * 4);
  int* degC = (int*)nxt((size_t)N * 4);
  int* offP = (int*)nxt((size_t)N * 4);
  int* offC = (int*)nxt((size_t)N * 4);
  int* curP = (int*)nxt((size_t)N * 4);
  int* curC = (int*)nxt((size_t)N * 4);
  int* posP = (int*)nxt((size_t)E * 4);
  int* posC = (int*)nxt((size_t)E * 4);
  int* selfS = (int*)nxt((size_t)E * 4);
  int* parS = (int*)nxt((size_t)E * 4);
  int* posCS = (int*)nxt((size_t)E * 4);
  int* partA = (int*)nxt(4096);
  int* partB = (int*)nxt(4096);
  unsigned short* Vw1t = (unsigned short*)nxt((size_t)128 * 256 * 2);
  unsigned short* Vw2t = (unsigned short*)nxt((size_t)256 * 128 * 2);
  unsigned short* Pw1t = (unsigned short*)nxt((size_t)256 * 256 * 2);
  unsigned short* Pw2t = (unsigned short*)nxt((size_t)256 * 128 * 2);
  unsigned short* Cw1t = (unsigned short*)nxt((size_t)256 * 256 * 2);
  unsigned short* Cw2t = (unsigned short*)nxt((size_t)256 * 128 * 2);
  unsigned short* Aw1t = (unsigned short*)nxt((size_t)384 * 256 * 2);
  unsigned short* Aw2t = (unsigned short*)nxt((size_t)256 * 128 * 2);
  float* b1P = (float*)nxt(256 * 4);
  float* b1C = (float*)nxt(256 * 4);
  unsigned short* Hbf = (unsigned short*)nxt((size_t)N * DD * 2);
  if ((size_t)(p - (char*)d_ws) > ws_size) Hbf = nullptr;

  hipMemsetAsync(degP, 0, (size_t)N * 4, stream);
  hipMemsetAsync(degC, 0, (size_t)N * 4, stream);

  auto blk = [](int total) { return dim3((total + 255) / 256); };
  wconv_all<<<blk(393216), 256, 0, stream>>>(Vw1, Vw2, Pw1, Pw2, Cw1, Cw2, Aw1, Aw2,
                                             Vw1t, Vw2t, Pw1t, Pw2t, Cw1t, Cw2t, Aw1t, Aw2t);

  prep_bias<<<1, 256, 0, stream>>>(Ew1, Eb1, Ew2, Eb2, Pw1, Pb1, Cw1, Cb1, b1P, b1C);
  count_k<<<blk(E), 256, 0, stream>>>(selfI, parI, degP, degC, E);

  int NB = (N + 1023) / 1024;
  scan1_2<<<dim3(NB, 2), 256, 0, stream>>>(degP, offP, partA, degC, offC, partB, N);
  scan2_2<<<2, 256, 0, stream>>>(partA, partB, NB);
  scan3copy<<<blk(N), 256, 0, stream>>>(offP, partA, curP, offC, partB, curC, N);
  pos_k<<<blk(E), 256, 0, stream>>>(selfI, parI, curP, curC, posP, posC, E);
  reorder_k<<<blk(E), 256, 0, stream>>>(selfI, parI, posP, posC, selfS, parS, posCS, E);

  dim3 gN((N + 63) / 64);
  int ET = (E + 63) / 64;
  int gEp = ET < 512 ? ET : 512;
  v_kernel<<<gN, 512, 0, stream>>>(batch, Vw1t, Vw2t, Vb1, Vb2, out, Hbf, N);

  for (int hop = 0; hop < 3; ++hop) {
    edge_kernel<<<gEp, 512, 0, stream>>>(out, Hbf, selfS, parS, posCS,
                                         Pw1t, Pw2t, Cw1t, Cw2t, b1P, b1C, Pb2, Cb2,
                                         SpE, ScE, E, ET);
    node_kernel<<<gN, 512, 0, stream>>>(out, (hop < 2) ? Hbf : (unsigned short*)nullptr,
                                        SpE, ScE, offP, degP, offC, degC,
                                        rootM, leafM, startT, endT,
                                        Aw1t, Aw2t, Ab1, Ab2, N);
  }
}

// Round 6
// 1871.240 us; speedup vs baseline: 1.2504x; 1.2504x over previous
//
#include <hip/hip_runtime.h>

typedef __attribute__((ext_vector_type(8))) short short8;
typedef __attribute__((ext_vector_type(4))) float f32x4;

#define DD 128
#define HH 256

__device__ __forceinline__ unsigned short f2bf(float f) {
  unsigned int u = __float_as_uint(f);
  u += 0x7fffu + ((u >> 16) & 1u);
  return (unsigned short)(u >> 16);
}
__device__ __forceinline__ float bf2f(unsigned short s) {
  return __uint_as_float(((unsigned int)s) << 16);
}
__device__ __forceinline__ f32x4 mfma16(short8 a, short8 b, f32x4 c) {
  return __builtin_amdgcn_mfma_f32_16x16x32_bf16(a, b, c, 0, 0, 0);
}
// LDS XOR swizzle: 16B-slot index XOR'd with row&7. Row strides are multiples
// of 32 dwords (128/256/384 shorts) so banks are fully determined by the slot:
// 8 XOR'd slots span all 32 banks -> 2 lanes/bank on b128 fragment reads (free).
__device__ __forceinline__ int swz8(int row, int colS) {
  return (((colS >> 3) ^ (row & 7)) << 3) | (colS & 7);
}

// ---- fused weight convert for all 8 matrices: dst[n][k] = bf16(src[(k+kswap)%K][n])
__global__ void wconv_all(const float* __restrict__ s0, const float* __restrict__ s1,
                          const float* __restrict__ s2, const float* __restrict__ s3,
                          const float* __restrict__ s4, const float* __restrict__ s5,
                          const float* __restrict__ s6, const float* __restrict__ s7,
                          unsigned short* __restrict__ d0, unsigned short* __restrict__ d1,
                          unsigned short* __restrict__ d2, unsigned short* __restrict__ d3,
                          unsigned short* __restrict__ d4, unsigned short* __restrict__ d5,
                          unsigned short* __restrict__ d6, unsigned short* __restrict__ d7) {
  int id = blockIdx.x * 256 + threadIdx.x;
  const float* src; unsigned short* dst; int K, Nout, kswap = 0, base;
  if (id < 32768)       { src = s0; dst = d0; K = 128; Nout = 256; base = 0; }
  else if (id < 65536)  { src = s1; dst = d1; K = 256; Nout = 128; base = 32768; }
  else if (id < 131072) { src = s2; dst = d2; K = 256; Nout = 256; base = 65536; kswap = 128; }
  else if (id < 163840) { src = s3; dst = d3; K = 256; Nout = 128; base = 131072; }
  else if (id < 229376) { src = s4; dst = d4; K = 256; Nout = 256; base = 163840; }
  else if (id < 262144) { src = s5; dst = d5; K = 256; Nout = 128; base = 229376; }
  else if (id < 360448) { src = s6; dst = d6; K = 384; Nout = 256; base = 262144; }
  else if (id < 393216) { src = s7; dst = d7; K = 256; Nout = 128; base = 360448; }
  else return;
  int lid = id - base;
  int n = lid / K, k = lid - n * K;
  int ks = k + kswap; if (ks >= K) ks -= K;
  dst[n * K + k] = f2bf(src[(size_t)ks * Nout + n]);
}

// ---- edge vectors + fold edge constants into layer-1 biases (1 block, 256 thr)
__global__ void prep_bias(const float* __restrict__ Ew1, const float* __restrict__ Eb1,
                          const float* __restrict__ Ew2, const float* __restrict__ Eb2,
                          const float* __restrict__ Pw1, const float* __restrict__ Pb1,
                          const float* __restrict__ Cw1, const float* __restrict__ Cb1,
                          float* __restrict__ b1P, float* __restrict__ b1C) {
  __shared__ float h1[HH], h0[HH], ein[DD], eout[DD];
  int t = threadIdx.x;
  h1[t] = fmaxf(Ew1[t] + Eb1[t], 0.f);
  h0[t] = fmaxf(Eb1[t], 0.f);
  __syncthreads();
  if (t < DD) {
    float s1 = Eb2[t], s0 = Eb2[t];
    for (int j = 0; j < HH; ++j) { s1 += h1[j] * Ew2[j * DD + t]; s0 += h0[j] * Ew2[j * DD + t]; }
    ein[t]  = fmaxf(s1, 0.f);
    eout[t] = fmaxf(s0, 0.f);
  }
  __syncthreads();
  float bp = Pb1[t], bc = Cb1[t];
  for (int d = 0; d < DD; ++d) {
    bp += eout[d] * Pw1[(size_t)(256 + d) * HH + t];
    bc += ein[d]  * Cw1[(size_t)(256 + d) * HH + t];
  }
  b1P[t] = bp; b1C[t] = bc;
}

// ---- CSR build
__global__ void count_k(const int* __restrict__ selfI, const int* __restrict__ parI,
                        int* degP, int* degC, int E) {
  int id = blockIdx.x * 256 + threadIdx.x;
  if (id < E) { atomicAdd(&degP[selfI[id]], 1); atomicAdd(&degC[parI[id]], 1); }
}

__global__ void scan1_2(const int* __restrict__ srcA, int* __restrict__ dstA, int* __restrict__ partA,
                        const int* __restrict__ srcB, int* __restrict__ dstB, int* __restrict__ partB,
                        int n) {
  const int* src = blockIdx.y ? srcB : srcA;
  int* dst = blockIdx.y ? dstB : dstA;
  int* part = blockIdx.y ? partB : partA;
  __shared__ int sh[256];
  int t = threadIdx.x;
  int base = blockIdx.x * 1024 + t * 4;
  int v0 = base + 0 < n ? src[base + 0] : 0;
  int v1 = base + 1 < n ? src[base + 1] : 0;
  int v2 = base + 2 < n ? src[base + 2] : 0;
  int v3 = base + 3 < n ? src[base + 3] : 0;
  int tsum = v0 + v1 + v2 + v3;
  sh[t] = tsum;
  __syncthreads();
  for (int off = 1; off < 256; off <<= 1) {
    int y = (t >= off) ? sh[t - off] : 0;
    __syncthreads();
    if (t >= off) sh[t] += y;
    __syncthreads();
  }
  int ex = sh[t] - tsum;
  if (base + 0 < n) dst[base + 0] = ex;
  if (base + 1 < n) dst[base + 1] = ex + v0;
  if (base + 2 < n) dst[base + 2] = ex + v0 + v1;
  if (base + 3 < n) dst[base + 3] = ex + v0 + v1 + v2;
  if (t == 255) part[blockIdx.x] = sh[255];
}

__global__ void scan2_2(int* __restrict__ partA, int* __restrict__ partB, int m) {
  int* part = blockIdx.x ? partB : partA;
  __shared__ int sh[256];
  int t = threadIdx.x;
  int carry = 0;
  for (int base = 0; base < m; base += 256) {
    int v = (base + t < m) ? part[base + t] : 0;
    sh[t] = v;
    __syncthreads();
    for (int off = 1; off < 256; off <<= 1) {
      int y = (t >= off) ? sh[t - off] : 0;
      __syncthreads();
      if (t >= off) sh[t] += y;
      __syncthreads();
    }
    if (base + t < m) part[base + t] = carry + sh[t] - v;
    int tot = sh[255];
    __syncthreads();
    carry += tot;
  }
}

__global__ void scan3copy(int* __restrict__ offP, const int* __restrict__ partA, int* __restrict__ curP,
                          int* __restrict__ offC, const int* __restrict__ partB, int* __restrict__ curC,
                          int n) {
  int i = blockIdx.x * 256 + threadIdx.x;
  if (i < n) {
    int a = offP[i] + partA[i >> 10];
    int b = offC[i] + partB[i >> 10];
    offP[i] = a; curP[i] = a;
    offC[i] = b; curC[i] = b;
  }
}

__global__ void pos_k(const int* __restrict__ selfI, const int* __restrict__ parI,
                      int* curP, int* curC, int* posP, int* posC, int E) {
  int e = blockIdx.x * 256 + threadIdx.x;
  if (e < E) {
    posP[e] = atomicAdd(&curP[selfI[e]], 1);
    posC[e] = atomicAdd(&curC[parI[e]], 1);
  }
}

// ---- CSR-P reorder (slot = posP[e], bijective)
__global__ void reorder_k(const int* __restrict__ selfI, const int* __restrict__ parI,
                          const int* __restrict__ posP, const int* __restrict__ posC,
                          int* __restrict__ selfS, int* __restrict__ parS,
                          int* __restrict__ posCS, int E) {
  int e = blockIdx.x * 256 + threadIdx.x;
  if (e < E) {
    int slot = posP[e];
    selfS[slot] = selfI[e];
    parS[slot] = parI[e];
    posCS[slot] = posC[e];
  }
}

// ---- cooperative MLP_V: 512 thr / 8 waves. K=128 -> 256 -> 128. Swizzled LDS.
__global__ __launch_bounds__(512, 4) void v_kernel(
    const float* __restrict__ x, const unsigned short* __restrict__ W1t,
    const unsigned short* __restrict__ W2t, const float* __restrict__ b1,
    const float* __restrict__ b2, float* __restrict__ hidden,
    unsigned short* __restrict__ hbf, int n) {
  __shared__ __align__(16) unsigned short A[64 * 128];
  __shared__ __align__(16) unsigned short O1[64 * 256];
  int t = threadIdx.x;
  int w = t >> 6, lane = t & 63, ln = lane & 15, quad = lane >> 4, qo = quad * 8;
  long tile0 = (long)blockIdx.x * 64;
  int rl = t >> 3, part = t & 7;
  int c0 = part * 16;
  long gr = tile0 + rl;
  const float* src = x + (size_t)(gr < n ? gr : 0) * DD + c0;
  unsigned short* arow = A + rl * 128;
#pragma unroll
  for (int i = 0; i < 4; ++i) {
    float4 v = *(const float4*)(src + i * 4);
    *(ushort4*)(arow + swz8(rl, c0 + i * 4)) =
        make_ushort4(f2bf(v.x), f2bf(v.y), f2bf(v.z), f2bf(v.w));
  }
  __syncthreads();
  f32x4 acc[4][2];
#pragma unroll
  for (int m = 0; m < 4; ++m) {
    acc[m][0] = {0.f, 0.f, 0.f, 0.f}; acc[m][1] = {0.f, 0.f, 0.f, 0.f};
  }
#pragma unroll
  for (int kt = 0; kt < 4; ++kt) {
    short8 a[4];
#pragma unroll
    for (int m = 0; m < 4; ++m) {
      int row = m * 16 + ln;
      a[m] = *(const short8*)(A + row * 128 + swz8(row, kt * 32 + qo));
    }
#pragma unroll
    for (int nn = 0; nn < 2; ++nn) {
      short8 b = *(const short8*)(W1t + (size_t)(w * 32 + nn * 16 + ln) * 128 + kt * 32 + qo);
#pragma unroll
      for (int m = 0; m < 4; ++m) acc[m][nn] = mfma16(a[m], b, acc[m][nn]);
    }
  }
#pragma unroll
  for (int nn = 0; nn < 2; ++nn) {
    int col = w * 32 + nn * 16 + ln;
    float bb = b1[col];
#pragma unroll
    for (int m = 0; m < 4; ++m)
#pragma unroll
      for (int r = 0; r < 4; ++r) {
        int row = m * 16 + quad * 4 + r;
        O1[row * 256 + swz8(row, col)] = f2bf(fmaxf(acc[m][nn][r] + bb, 0.f));
      }
  }
  __syncthreads();
  f32x4 acc2[4];
#pragma unroll
  for (int m = 0; m < 4; ++m) acc2[m] = {0.f, 0.f, 0.f, 0.f};
#pragma unroll
  for (int kt = 0; kt < 8; ++kt) {
    short8 b = *(const short8*)(W2t + (size_t)(w * 16 + ln) * 256 + kt * 32 + qo);
#pragma unroll
    for (int m = 0; m < 4; ++m) {
      int row = m * 16 + ln;
      short8 a = *(const short8*)(O1 + row * 256 + swz8(row, kt * 32 + qo));
      acc2[m] = mfma16(a, b, acc2[m]);
    }
  }
  {
    int col = w * 16 + ln;
    float bb = b2[col];
#pragma unroll
    for (int m = 0; m < 4; ++m)
#pragma unroll
      for (int r = 0; r < 4; ++r) {
        long gr2 = tile0 + m * 16 + quad * 4 + r;
        if (gr2 < n) {
          float v = fmaxf(acc2[m][r] + bb, 0.f);
          hidden[gr2 * DD + col] = v;
          if (hbf) hbf[gr2 * DD + col] = f2bf(v);
        }
      }
  }
}

// ---- cooperative edge kernel (CSR-P ordered): 512 thr / 8 waves, M=64 slots.
// P+C layer-1 fused over one A-tile read. Swizzled LDS (A, O1).
__global__ __launch_bounds__(512, 4) void edge_kernel(
    const float* __restrict__ hidden, const unsigned short* __restrict__ hbf,
    const int* __restrict__ selfS, const int* __restrict__ parS,
    const int* __restrict__ posCS,
    const unsigned short* __restrict__ Pw1t, const unsigned short* __restrict__ Pw2t,
    const unsigned short* __restrict__ Cw1t, const unsigned short* __restrict__ Cw2t,
    const float* __restrict__ b1P, const float* __restrict__ b1C,
    const float* __restrict__ b2P, const float* __restrict__ b2C,
    unsigned short* __restrict__ SpE, unsigned short* __restrict__ ScE, int E) {
  __shared__ __align__(16) unsigned short A[64 * 256];   // [hs|hp] bf16 tile
  __shared__ __align__(16) unsigned short O1[64 * 256];  // layer-1 out / repack buf
  int t = threadIdx.x;
  int w = t >> 6, lane = t & 63, ln = lane & 15, quad = lane >> 4, qo = quad * 8;
  long tile0 = (long)blockIdx.x * 64;
  int rl = t >> 3, part = t & 7;
  long ge = tile0 + rl;
  bool vrow = ge < E;
  int si = vrow ? selfS[ge] : 0;
  int pi = vrow ? parS[ge] : 0;
  unsigned short* arow = A + rl * 256;
  if (hbf) {
    const unsigned short* srcb = (part < 4) ? (hbf + (size_t)si * DD + part * 32)
                                            : (hbf + (size_t)pi * DD + (part - 4) * 32);
#pragma unroll
    for (int i = 0; i < 4; ++i)
      *(short8*)(arow + swz8(rl, part * 32 + i * 8)) = *(const short8*)(srcb + i * 8);
  } else {
    const float* src = (part < 4) ? (hidden + (size_t)si * DD + part * 32)
                                  : (hidden + (size_t)pi * DD + (part - 4) * 32);
#pragma unroll
    for (int i = 0; i < 8; ++i) {
      float4 v = *(const float4*)(src + i * 4);
      *(ushort4*)(arow + swz8(rl, part * 32 + i * 4)) =
          make_ushort4(f2bf(v.x), f2bf(v.y), f2bf(v.z), f2bf(v.w));
    }
  }
  __syncthreads();

  // fused layer 1 for P and C: one a[4] read feeds 16 MFMAs
  f32x4 accP[4][2], accC[4][2];
#pragma unroll
  for (int m = 0; m < 4; ++m) {
    accP[m][0] = {0.f, 0.f, 0.f, 0.f}; accP[m][1] = {0.f, 0.f, 0.f, 0.f};
    accC[m][0] = {0.f, 0.f, 0.f, 0.f}; accC[m][1] = {0.f, 0.f, 0.f, 0.f};
  }
#pragma unroll
  for (int kt = 0; kt < 8; ++kt) {
    short8 a[4];
#pragma unroll
    for (int m = 0; m < 4; ++m) {
      int row = m * 16 + ln;
      a[m] = *(const short8*)(A + row * 256 + swz8(row, kt * 32 + qo));
    }
#pragma unroll
    for (int nn = 0; nn < 2; ++nn) {
      short8 bp = *(const short8*)(Pw1t + (size_t)(w * 32 + nn * 16 + ln) * 256 + kt * 32 + qo);
      short8 bc = *(const short8*)(Cw1t + (size_t)(w * 32 + nn * 16 + ln) * 256 + kt * 32 + qo);
#pragma unroll
      for (int m = 0; m < 4; ++m) {
        accP[m][nn] = mfma16(a[m], bp, accP[m][nn]);
        accC[m][nn] = mfma16(a[m], bc, accC[m][nn]);
      }
    }
  }
  // no barrier: A and O1 are distinct buffers; O1 has no readers yet

#pragma unroll
  for (int mlp = 0; mlp < 2; ++mlp) {
    const unsigned short* W2t = mlp ? Cw2t : Pw2t;
    const float* b1 = mlp ? b1C : b1P;
    const float* b2 = mlp ? b2C : b2P;
    unsigned short* Sout = mlp ? ScE : SpE;
    // write O1 = relu(acc + b1)
#pragma unroll
    for (int nn = 0; nn < 2; ++nn) {
      int col = w * 32 + nn * 16 + ln;
      float bb = b1[col];
#pragma unroll
      for (int m = 0; m < 4; ++m)
#pragma unroll
        for (int r = 0; r < 4; ++r) {
          float v = mlp ? accC[m][nn][r] : accP[m][nn][r];
          int row = m * 16 + quad * 4 + r;
          O1[row * 256 + swz8(row, col)] = f2bf(fmaxf(v + bb, 0.f));
        }
    }
    __syncthreads();
    // layer 2: wave w -> cols [w*16, w*16+16)
    f32x4 acc2[4];
#pragma unroll
    for (int m = 0; m < 4; ++m) acc2[m] = {0.f, 0.f, 0.f, 0.f};
#pragma unroll
    for (int kt = 0; kt < 8; ++kt) {
      short8 b = *(const short8*)(W2t + (size_t)(w * 16 + ln) * 256 + kt * 32 + qo);
#pragma unroll
      for (int m = 0; m < 4; ++m) {
        int row = m * 16 + ln;
        short8 a = *(const short8*)(O1 + row * 256 + swz8(row, kt * 32 + qo));
        acc2[m] = mfma16(a, b, acc2[m]);
      }
    }
    __syncthreads();  // O1 reads done -> safe to overwrite with repack
    {
      int col = w * 16 + ln;
      float bb = b2[col];
#pragma unroll
      for (int m = 0; m < 4; ++m)
#pragma unroll
        for (int r = 0; r < 4; ++r) {
          int row = m * 16 + quad * 4 + r;
          O1[row * 256 + swz8(row, col)] = f2bf(fmaxf(acc2[m][r] + bb, 0.f));
        }
    }
    __syncthreads();
    // store rows: P -> contiguous slot ge; C -> CSR-C position (random)
    if (vrow) {
      size_t dpos = mlp ? (size_t)posCS[ge] : (size_t)ge;
      ushort4* dst = (ushort4*)(Sout + dpos * DD + part * 16);
#pragma unroll
      for (int i = 0; i < 4; ++i)
        dst[i] = *(const ushort4*)(O1 + rl * 256 + swz8(rl, part * 16 + i * 4));
    }
    __syncthreads();  // store LDS-reads done before next mlp overwrites O1
  }
}

// ---- cooperative node kernel: CSR gather-mean, build [h|S_p|S_c], MLP_A
// (K=384), residual add. 512 thr, O1 overlaid on A. Swizzled LDS.
__global__ __launch_bounds__(512, 4) void node_kernel(
    float* __restrict__ hidden, unsigned short* __restrict__ hbf,
    const unsigned short* __restrict__ SpE, const unsigned short* __restrict__ ScE,
    const int* __restrict__ offP, const int* __restrict__ degP,
    const int* __restrict__ offC, const int* __restrict__ degC,
    const float* __restrict__ rootM, const float* __restrict__ leafM,
    const float* __restrict__ startT, const float* __restrict__ endT,
    const unsigned short* __restrict__ W1t, const unsigned short* __restrict__ W2t,
    const float* __restrict__ b1, const float* __restrict__ b2, int n) {
  __shared__ __align__(16) unsigned short A[64 * 384];
  int t = threadIdx.x;
  int w = t >> 6, lane = t & 63, ln = lane & 15, quad = lane >> 4, qo = quad * 8;
  long tile0 = (long)blockIdx.x * 64;
  int rl = t >> 3, part = t & 7;
  int c0 = part * 16;
  long gr = tile0 + rl;
  long g = (gr < n) ? gr : 0;
  unsigned short* arow = A + rl * 384;
  if (hbf) {  // h cols from bf16 mirror
    const unsigned short* hrowb = hbf + (size_t)g * DD + c0;
    *(short8*)(arow + swz8(rl, c0))     = *(const short8*)(hrowb);
    *(short8*)(arow + swz8(rl, c0 + 8)) = *(const short8*)(hrowb + 8);
  } else {
    const float* hrow = hidden + (size_t)g * DD + c0;
#pragma unroll
    for (int i = 0; i < 4; ++i) {
      float4 h = *(const float4*)(hrow + i * 4);
      *(ushort4*)(arow + swz8(rl, c0 + i * 4)) =
          make_ushort4(f2bf(h.x), f2bf(h.y), f2bf(h.z), f2bf(h.w));
    }
  }
  {  // S_p mean: contiguous CSR rows
    int off = offP[g], dg = degP[g];
    float s[16];
#pragma unroll
    for (int i = 0; i < 16; ++i) s[i] = 0.f;
    for (int j = 0; j < dg; ++j) {
      const unsigned short* rr = SpE + (size_t)(off + j) * DD + c0;
#pragma unroll
      for (int i = 0; i < 4; ++i) {
        ushort4 u = *(const ushort4*)(rr + i * 4);
        s[i * 4 + 0] += bf2f(u.x); s[i * 4 + 1] += bf2f(u.y);
        s[i * 4 + 2] += bf2f(u.z); s[i * 4 + 3] += bf2f(u.w);
      }
    }
    float ip = 1.f / fmaxf((float)dg, 1.f);
    float rm = rootM[g];
#pragma unroll
    for (int i = 0; i < 4; ++i) {
      float4 st = *(const float4*)(startT + c0 + i * 4);
      *(ushort4*)(arow + swz8(rl, 128 + c0 + i * 4)) = make_ushort4(
          f2bf(s[i * 4 + 0] * ip + rm * st.x), f2bf(s[i * 4 + 1] * ip + rm * st.y),
          f2bf(s[i * 4 + 2] * ip + rm * st.z), f2bf(s[i * 4 + 3] * ip + rm * st.w));
    }
  }
  {  // S_c mean
    int off = offC[g], dg = degC[g];
    float s[16];
#pragma unroll
    for (int i = 0; i < 16; ++i) s[i] = 0.f;
    for (int j = 0; j < dg; ++j) {
      const unsigned short* rr = ScE + (size_t)(off + j) * DD + c0;
#pragma unroll
      for (int i = 0; i < 4; ++i) {
        ushort4 u = *(const ushort4*)(rr + i * 4);
        s[i * 4 + 0] += bf2f(u.x); s[i * 4 + 1] += bf2f(u.y);
        s[i * 4 + 2] += bf2f(u.z); s[i * 4 + 3] += bf2f(u.w);
      }
    }
    float ic = 1.f / fmaxf((float)dg, 1.f);
    float lm = leafM[g];
#pragma unroll
    for (int i = 0; i < 4; ++i) {
      float4 et = *(const float4*)(endT + c0 + i * 4);
      *(ushort4*)(arow + swz8(rl, 256 + c0 + i * 4)) = make_ushort4(
          f2bf(s[i * 4 + 0] * ic + lm * et.x), f2bf(s[i * 4 + 1] * ic + lm * et.y),
          f2bf(s[i * 4 + 2] * ic + lm * et.z), f2bf(s[i * 4 + 3] * ic + lm * et.w));
    }
  }
  __syncthreads();
  // layer 1 (K=384): wave w -> cols [w*32, w*32+32)
  f32x4 acc[4][2];
#pragma unroll
  for (int m = 0; m < 4; ++m) {
    acc[m][0] = {0.f, 0.f, 0.f, 0.f}; acc[m][1] = {0.f, 0.f, 0.f, 0.f};
  }
#pragma unroll
  for (int kt = 0; kt < 12; ++kt) {
    short8 a[4];
#pragma unroll
    for (int m = 0; m < 4; ++m) {
      int row = m * 16 + ln;
      a[m] = *(const short8*)(A + row * 384 + swz8(row, kt * 32 + qo));
    }
#pragma unroll
    for (int nn = 0; nn < 2; ++nn) {
      short8 b = *(const short8*)(W1t + (size_t)(w * 32 + nn * 16 + ln) * 384 + kt * 32 + qo);
#pragma unroll
      for (int m = 0; m < 4; ++m) acc[m][nn] = mfma16(a[m], b, acc[m][nn]);
    }
  }
  __syncthreads();  // all A reads done -> overlay O1 into A storage
#pragma unroll
  for (int nn = 0; nn < 2; ++nn) {
    int col = w * 32 + nn * 16 + ln;
    float bb = b1[col];
#pragma unroll
    for (int m = 0; m < 4; ++m)
#pragma unroll
      for (int r = 0; r < 4; ++r) {
        int row = m * 16 + quad * 4 + r;
        A[row * 384 + swz8(row, col)] = f2bf(fmaxf(acc[m][nn][r] + bb, 0.f));
      }
  }
  __syncthreads();
  // layer 2 (K=256): wave w -> cols [w*16, w*16+16)
  f32x4 acc2[4];
#pragma unroll
  for (int m = 0; m < 4; ++m) acc2[m] = {0.f, 0.f, 0.f, 0.f};
#pragma unroll
  for (int kt = 0; kt < 8; ++kt) {
    short8 b = *(const short8*)(W2t + (size_t)(w * 16 + ln) * 256 + kt * 32 + qo);
#pragma unroll
    for (int m = 0; m < 4; ++m) {
      int row = m * 16 + ln;
      short8 a = *(const short8*)(A + row * 384 + swz8(row, kt * 32 + qo));
      acc2[m] = mfma16(a, b, acc2[m]);
    }
  }
  __syncthreads();  // O1 reads done -> overlay fp32 repack (residual in fp32)
  {
    int col = w * 16 + ln;
    float bb = b2[col];
#pragma unroll
    for (int m = 0; m < 4; ++m)
#pragma unroll
      for (int r = 0; r < 4; ++r) {
        int row = m * 16 + quad * 4 + r;
        *(float*)(A + row * 384 + swz8(row, col * 2)) = fmaxf(acc2[m][r] + bb, 0.f);
      }
  }
  __syncthreads();
  if (gr < n) {
    float* hrow = hidden + (size_t)gr * DD + c0;
    unsigned short* brow = hbf ? hbf + (size_t)gr * DD + c0 : nullptr;
#pragma unroll
    for (int i = 0; i < 4; ++i) {
      float4 v = *(const float4*)(A + rl * 384 + swz8(rl, part * 32 + i * 8));
      float4 h = *(const float4*)(hrow + i * 4);
      h.x += v.x; h.y += v.y; h.z += v.z; h.w += v.w;
      *(float4*)(hrow + i * 4) = h;
      if (brow)
        *(ushort4*)(brow + i * 4) = make_ushort4(f2bf(h.x), f2bf(h.y), f2bf(h.z), f2bf(h.w));
    }
  }
}

extern "C" void kernel_launch(void* const* d_in, const int* in_sizes, int n_in,
                              void* d_out, int out_size, void* d_ws, size_t ws_size,
                              hipStream_t stream) {
  const float* batch  = (const float*)d_in[0];
  const int*   selfI  = (const int*)d_in[1];
  const int*   parI   = (const int*)d_in[2];
  const float* rootM  = (const float*)d_in[3];
  const float* leafM  = (const float*)d_in[4];
  const float* startT = (const float*)d_in[5];
  const float* endT   = (const float*)d_in[6];
  const float* Vw1 = (const float*)d_in[7],  *Vb1 = (const float*)d_in[8];
  const float* Vw2 = (const float*)d_in[9],  *Vb2 = (const float*)d_in[10];
  const float* Ew1 = (const float*)d_in[11], *Eb1 = (const float*)d_in[12];
  const float* Ew2 = (const float*)d_in[13], *Eb2 = (const float*)d_in[14];
  const float* Pw1 = (const float*)d_in[15], *Pb1 = (const float*)d_in[16];
  const float* Pw2 = (const float*)d_in[17], *Pb2 = (const float*)d_in[18];
  const float* Cw1 = (const float*)d_in[19], *Cb1 = (const float*)d_in[20];
  const float* Cw2 = (const float*)d_in[21], *Cb2 = (const float*)d_in[22];
  const float* Aw1 = (const float*)d_in[23], *Ab1 = (const float*)d_in[24];
  const float* Aw2 = (const float*)d_in[25], *Ab2 = (const float*)d_in[26];

  const int N = in_sizes[3];
  const int E = in_sizes[1];
  float* out = (float*)d_out;

  char* p = (char*)d_ws;
  auto nxt = [&](size_t sz) { char* r = p; p += (sz + 255) & ~(size_t)255; return r; };
  unsigned short* SpE = (unsigned short*)nxt((size_t)E * DD * 2);
  unsigned short* ScE = (unsigned short*)nxt((size_t)E * DD * 2);
  int* degP = (int*)nxt((size_t)N * 4);
  int* degC = (int*)nxt((size_t)N * 4);
  int* offP = (int*)nxt((size_t)N * 4);
  int* offC = (int*)nxt((size_t)N * 4);
  int* curP = (int*)nxt((size_t)N * 4);
  int* curC = (int*)nxt((size_t)N * 4);
  int* posP = (int*)nxt((size_t)E * 4);
  int* posC = (int*)nxt((size_t)E * 4);
  int* selfS = (int*)nxt((size_t)E * 4);
  int* parS = (int*)nxt((size_t)E * 4);
  int* posCS = (int*)nxt((size_t)E * 4);
  int* partA = (int*)nxt(4096);
  int* partB = (int*)nxt(4096);
  unsigned short* Vw1t = (unsigned short*)nxt((size_t)128 * 256 * 2);
  unsigned short* Vw2t = (unsigned short*)nxt((size_t)256 * 128 * 2);
  unsigned short* Pw1t = (unsigned short*)nxt((size_t)256 * 256 * 2);
  unsigned short* Pw2t = (unsigned short*)nxt((size_t)256 * 128 * 2);
  unsigned short* Cw1t = (unsigned short*)nxt((size_t)256 * 256 * 2);
  unsigned short* Cw2t = (unsigned short*)nxt((size_t)256 * 128 * 2);
  unsigned short* Aw1t = (unsigned short*)nxt((size_t)384 * 256 * 2);
  unsigned short* Aw2t = (unsigned short*)nxt((size_t)256 * 128 * 2);
  float* b1P = (float*)nxt(256 * 4);
  float* b1C = (float*)nxt(256 * 4);
  unsigned short* Hbf = (unsigned short*)nxt((size_t)N * DD * 2);
  if ((size_t)(p - (char*)d_ws) > ws_size) Hbf = nullptr;

  hipMemsetAsync(degP, 0, (size_t)N * 4, stream);
  hipMemsetAsync(degC, 0, (size_t)N * 4, stream);

  auto blk = [](int total) { return dim3((total + 255) / 256); };
  wconv_all<<<blk(393216), 256, 0, stream>>>(Vw1, Vw2, Pw1, Pw2, Cw1, Cw2, Aw1, Aw2,
                                             Vw1t, Vw2t, Pw1t, Pw2t, Cw1t, Cw2t, Aw1t, Aw2t);

  prep_bias<<<1, 256, 0, stream>>>(Ew1, Eb1, Ew2, Eb2, Pw1, Pb1, Cw1, Cb1, b1P, b1C);
  count_k<<<blk(E), 256, 0, stream>>>(selfI, parI, degP, degC, E);

  int NB = (N + 1023) / 1024;
  scan1_2<<<dim3(NB, 2), 256, 0, stream>>>(degP, offP, partA, degC, offC, partB, N);
  scan2_2<<<2, 256, 0, stream>>>(partA, partB, NB);
  scan3copy<<<blk(N), 256, 0, stream>>>(offP, partA, curP, offC, partB, curC, N);
  pos_k<<<blk(E), 256, 0, stream>>>(selfI, parI, curP, curC, posP, posC, E);
  reorder_k<<<blk(E), 256, 0, stream>>>(selfI, parI, posP, posC, selfS, parS, posCS, E);

  dim3 gN((N + 63) / 64), gE((E + 63) / 64);
  v_kernel<<<gN, 512, 0, stream>>>(batch, Vw1t, Vw2t, Vb1, Vb2, out, Hbf, N);

  for (int hop = 0; hop < 3; ++hop) {
    edge_kernel<<<gE, 512, 0, stream>>>(out, Hbf, selfS, parS, posCS,
                                        Pw1t, Pw2t, Cw1t, Cw2t, b1P, b1C, Pb2, Cb2,
                                        SpE, ScE, E);
    node_kernel<<<gN, 512, 0, stream>>>(out, (hop < 2) ? Hbf : (unsigned short*)nullptr,
                                        SpE, ScE, offP, degP, offC, degC,
                                        rootM, leafM, startT, endT,
                                        Aw1t, Aw2t, Ab1, Ab2, N);
  }
}